// Round 1
// baseline (453.207 us; speedup 1.0000x reference)
//
#include <hip/hip_runtime.h>
#include <math.h>

#define N_QUBITS 12
#define DIM 4096
#define N_LAYERS 4
#define N_ACTIONS 6
#define BATCH 4096
#define BLOCK 256
#define AMPS_PER_THREAD (DIM / BLOCK)      // 16
#define PAIRS_PER_THREAD (DIM / 2 / BLOCK) // 8

__global__ __launch_bounds__(BLOCK) void qdqn_kernel(
    const float* __restrict__ x,       // [BATCH,12]
    const float* __restrict__ weights, // [4,12,3]
    const float* __restrict__ fc_w,    // [6,12]
    const float* __restrict__ fc_b,    // [6]
    float* __restrict__ out)           // [BATCH,6]
{
    __shared__ float sre[DIM];
    __shared__ float sim[DIM];
    __shared__ float rot[N_LAYERS * N_QUBITS][8]; // u00r,u00i,u01r,u01i,u10r,u10i,u11r,u11i
    __shared__ float encc[N_QUBITS], encs[N_QUBITS];
    __shared__ float red[4][N_QUBITS];
    __shared__ float qout[N_QUBITS];

    const int tid = threadIdx.x;
    const int b = blockIdx.x;

    // --- Precompute the 48 Rot matrices (batch-independent, wave-uniform use) ---
    if (tid < N_LAYERS * N_QUBITS) {
        float phi = weights[tid * 3 + 0];
        float theta = weights[tid * 3 + 1];
        float omega = weights[tid * 3 + 2];
        float st, ct, sa, ca, sb, cb;
        sincosf(0.5f * theta, &st, &ct);
        sincosf(0.5f * (phi + omega), &sa, &ca);
        sincosf(0.5f * (phi - omega), &sb, &cb);
        // u00 = (ca - i sa) ct ; u01 = -(cb + i sb) st
        // u10 = (cb - i sb) st ; u11 = (ca + i sa) ct
        rot[tid][0] = ca * ct;  rot[tid][1] = -sa * ct;
        rot[tid][2] = -cb * st; rot[tid][3] = -sb * st;
        rot[tid][4] = cb * st;  rot[tid][5] = -sb * st;
        rot[tid][6] = ca * ct;  rot[tid][7] = sa * ct;
    }
    // --- Encoding angles for this batch element ---
    if (tid >= 64 && tid < 64 + N_QUBITS) {
        int q = tid - 64;
        float xv = x[b * N_QUBITS + q];
        float s, c;
        sincosf(0.5f * xv, &s, &c);
        encc[q] = c;
        encs[q] = s;
    }
    __syncthreads();

    // --- Build RY-encoded product state directly: amp(i) = prod_q (bit? s_q : c_q) ---
    // i = tid*16 + j : tid supplies wires 0..7 (MSBs), j supplies wires 8..11.
    {
        float pre = 1.0f;
#pragma unroll
        for (int q = 0; q < 8; ++q) {
            int bit = (tid >> (7 - q)) & 1;
            pre *= bit ? encs[q] : encc[q];
        }
#pragma unroll
        for (int j = 0; j < AMPS_PER_THREAD; ++j) {
            float v = pre;
#pragma unroll
            for (int q = 8; q < 12; ++q) {
                int bit = (j >> (11 - q)) & 1;
                v *= bit ? encs[q] : encc[q];
            }
            sre[tid * AMPS_PER_THREAD + j] = v;
            sim[tid * AMPS_PER_THREAD + j] = 0.0f;
        }
    }
    __syncthreads();

    // --- 4 layers x 12 Rot gates; CZ diag fused into the q==11 store ---
    for (int l = 0; l < N_LAYERS; ++l) {
        for (int q = 0; q < N_QUBITS; ++q) {
            const float* m = rot[l * N_QUBITS + q];
            const float u00r = m[0], u00i = m[1], u01r = m[2], u01i = m[3];
            const float u10r = m[4], u10i = m[5], u11r = m[6], u11i = m[7];
            const int st = 1 << (N_QUBITS - 1 - q);
            const bool last = (q == N_QUBITS - 1);
#pragma unroll
            for (int r = 0; r < PAIRS_PER_THREAD; ++r) {
                int p = r * BLOCK + tid;
                int i0 = ((p & ~(st - 1)) << 1) | (p & (st - 1));
                int i1 = i0 + st;
                float a0r = sre[i0], a0i = sim[i0];
                float a1r = sre[i1], a1i = sim[i1];
                float n0r = u00r * a0r - u00i * a0i + u01r * a1r - u01i * a1i;
                float n0i = u00r * a0i + u00i * a0r + u01r * a1i + u01i * a1r;
                float n1r = u10r * a0r - u10i * a0i + u11r * a1r - u11i * a1i;
                float n1i = u10r * a0i + u10i * a0r + u11r * a1i + u11i * a1r;
                if (last) {
                    float s0 = (__popc(i0 & (i0 >> 1)) & 1) ? -1.0f : 1.0f;
                    float s1 = (__popc(i1 & (i1 >> 1)) & 1) ? -1.0f : 1.0f;
                    n0r *= s0; n0i *= s0;
                    n1r *= s1; n1i *= s1;
                }
                sre[i0] = n0r; sim[i0] = n0i;
                sre[i1] = n1r; sim[i1] = n1i;
            }
            __syncthreads();
        }
    }

    // --- Z-expectations: wires 0..7 sign is uniform over a thread's 16 amps ---
    float tot = 0.f, low0 = 0.f, low1 = 0.f, low2 = 0.f, low3 = 0.f;
#pragma unroll
    for (int j = 0; j < AMPS_PER_THREAD; ++j) {
        int i = tid * AMPS_PER_THREAD + j;
        float pr = sre[i], pi = sim[i];
        float p = pr * pr + pi * pi;
        tot += p;
        low0 += (j & 8) ? -p : p; // wire 8
        low1 += (j & 4) ? -p : p; // wire 9
        low2 += (j & 2) ? -p : p; // wire 10
        low3 += (j & 1) ? -p : p; // wire 11
    }
    float part[N_QUBITS];
#pragma unroll
    for (int q = 0; q < 8; ++q)
        part[q] = ((tid >> (7 - q)) & 1) ? -tot : tot;
    part[8] = low0; part[9] = low1; part[10] = low2; part[11] = low3;

    // wave (64-lane) shuffle reduction, then cross-wave via LDS
#pragma unroll
    for (int o = 32; o > 0; o >>= 1) {
#pragma unroll
        for (int q = 0; q < N_QUBITS; ++q)
            part[q] += __shfl_down(part[q], o);
    }
    int wave = tid >> 6, lane = tid & 63;
    if (lane == 0) {
#pragma unroll
        for (int q = 0; q < N_QUBITS; ++q)
            red[wave][q] = part[q];
    }
    __syncthreads();
    if (tid < N_QUBITS) {
        qout[tid] = red[0][tid] + red[1][tid] + red[2][tid] + red[3][tid];
    }
    __syncthreads();

    // --- tiny 12 -> 6 linear head ---
    if (tid < N_ACTIONS) {
        float acc = fc_b[tid];
#pragma unroll
        for (int q = 0; q < N_QUBITS; ++q)
            acc += qout[q] * fc_w[tid * N_QUBITS + q];
        out[b * N_ACTIONS + tid] = acc;
    }
}

extern "C" void kernel_launch(void* const* d_in, const int* in_sizes, int n_in,
                              void* d_out, int out_size, void* d_ws, size_t ws_size,
                              hipStream_t stream) {
    const float* x   = (const float*)d_in[0];
    const float* w   = (const float*)d_in[1];
    const float* fcw = (const float*)d_in[2];
    const float* fcb = (const float*)d_in[3];
    qdqn_kernel<<<BATCH, BLOCK, 0, stream>>>(x, w, fcw, fcb, (float*)d_out);
}

// Round 2
// 229.336 us; speedup vs baseline: 1.9762x; 1.9762x over previous
//
#include <hip/hip_runtime.h>
#include <math.h>

#define NQ 12
#define DIM 4096
#define NL 4
#define NA 6
#define BATCH 4096
#define TROW 65  // odd float stride -> conflict-free transpose both directions

// Layouts: P0: amp index i = (lane<<6)|j  (lane bits = wires 0..5, j bits = wires 6..11)
//          P1: amp index i = (j<<6)|lane  (j bits = wires 0..5, lane bits = wires 6..11)
// Per layer, single-qubit Rot gates commute among themselves; CZ is diagonal and
// applicable in any layout. Session schedule (g = 0..7, layer l = g>>1,
// hi = gates on wires 6..11 i.e. layout P0):
//   g even: apply 6 gates, then transpose (P0<->P1)
//   g odd : apply 6 gates, then CZ diagonal
// Sequence: G0(L0 hi,P0) T G1(L0 lo,P1) CZ0 G2(L1 lo,P1) T G3(L1 hi,P0) CZ1
//           G4(L2 hi,P0) T G5(L2 lo,P1) CZ2 G6(L3 lo,P1) T G7(L3 hi,P0) CZ3, measure in P0.

__global__ __launch_bounds__(64) void qdqn_kernel(
    const float* __restrict__ x,       // [BATCH,12]
    const float* __restrict__ weights, // [4,12,3]
    const float* __restrict__ fc_w,    // [6,12]
    const float* __restrict__ fc_b,    // [6]
    float* __restrict__ out)           // [BATCH,6]
{
    __shared__ __align__(16) float tbuf[64 * TROW];     // 16640 B transpose buffer
    __shared__ __align__(16) float rotc[NL * NQ][8];    // u00r,u00i,u01r,u01i,u10r,u10i,u11r,u11i
    __shared__ float encc[NQ], encs[NQ];
    __shared__ float redq[NQ];

    const int lane = threadIdx.x;
    const int b = blockIdx.x;

    // --- per-block setup: 48 rot matrices (lanes 0..47), encoding sincos (lanes 48..59)
    if (lane < NL * NQ) {
        float phi = weights[lane * 3 + 0];
        float th  = weights[lane * 3 + 1];
        float om  = weights[lane * 3 + 2];
        float st, ct, sa, ca, sb, cb;
        sincosf(0.5f * th, &st, &ct);
        sincosf(0.5f * (phi + om), &sa, &ca);
        sincosf(0.5f * (phi - om), &sb, &cb);
        rotc[lane][0] =  ca * ct; rotc[lane][1] = -sa * ct;  // u00
        rotc[lane][2] = -cb * st; rotc[lane][3] = -sb * st;  // u01
        rotc[lane][4] =  cb * st; rotc[lane][5] = -sb * st;  // u10
        rotc[lane][6] =  ca * ct; rotc[lane][7] =  sa * ct;  // u11
    } else if (lane < NL * NQ + NQ) {
        int q = lane - NL * NQ;
        float s, c;
        sincosf(0.5f * x[b * NQ + q], &s, &c);
        encc[q] = c; encs[q] = s;
    }
    __syncthreads();

    float ec[NQ], es[NQ];
#pragma unroll
    for (int q = 0; q < NQ; ++q) { ec[q] = encc[q]; es[q] = encs[q]; }

    // --- build RY product state in P0 ---
    float re[64], im[64];
    float pre = 1.0f;
#pragma unroll
    for (int q = 0; q < 6; ++q)  // wire q (0..5) <-> lane bit (5-q)
        pre *= ((lane >> (5 - q)) & 1) ? es[q] : ec[q];
#pragma unroll
    for (int j = 0; j < 64; ++j) {
        float v = pre;
#pragma unroll
        for (int q = 6; q < NQ; ++q)  // wire q (6..11) <-> j bit (11-q)
            v *= ((j >> (11 - q)) & 1) ? es[q] : ec[q];
        re[j] = v;
        im[j] = 0.0f;
    }

    // lane-internal CZ sign factor (5 adjacent-bit pairs within the lane's 6 bits)
    const float slane = (__popc(lane & (lane >> 1)) & 1) ? -1.0f : 1.0f;

#pragma unroll 1
    for (int g = 0; g < 8; ++g) {
        const int l = g >> 1;
        const bool hi = (((g + 1) & 2) == 0);  // true: wires 6..11 local (layout P0)

        // --- 6 register-local gates on j-bits 0..5 ---
#pragma unroll
        for (int bit = 0; bit < 6; ++bit) {
            const int wire = hi ? (11 - bit) : (5 - bit);
            const float4 cA = *((float4*)&rotc[l * NQ + wire][0]);
            const float4 cB = *((float4*)&rotc[l * NQ + wire][4]);
            const float u00r = cA.x, u00i = cA.y, u01r = cA.z, u01i = cA.w;
            const float u10r = cB.x, u10i = cB.y, u11r = cB.z, u11i = cB.w;
            const int S = 1 << bit;
#pragma unroll
            for (int m = 0; m < 32; ++m) {
                const int j0 = ((m & ~(S - 1)) << 1) | (m & (S - 1));
                const int j1 = j0 + S;
                const float a0r = re[j0], a0i = im[j0];
                const float a1r = re[j1], a1i = im[j1];
                re[j0] = u00r * a0r - u00i * a0i + u01r * a1r - u01i * a1i;
                im[j0] = u00r * a0i + u00i * a0r + u01r * a1i + u01i * a1r;
                re[j1] = u10r * a0r - u10i * a0i + u11r * a1r - u11i * a1i;
                im[j1] = u10r * a0i + u10i * a0r + u11r * a1i + u11i * a1r;
            }
        }

        if (g & 1) {
            // --- CZ diagonal in current layout ---
            // P0: i=(lane<<6)|j  -> boundary pair (bit6,bit5) = (lane&1, j>>5)
            // P1: i=(j<<6)|lane  -> boundary pair = (j&1, lane>>5)
            const float flip = ((hi ? lane : (lane >> 5)) & 1) ? -slane : slane;
#pragma unroll
            for (int j = 0; j < 64; ++j) {
                const float fb0 = (hi ? (j >= 32) : ((j & 1) != 0)) ? flip : slane;
                const float f = (__popc(j & (j >> 1)) & 1) ? -fb0 : fb0;  // compile-time sign
                re[j] *= f;
                im[j] *= f;
            }
        } else {
            // --- 64x64 transpose through LDS (conflict-free via odd row stride) ---
            __syncthreads();  // WAR vs previous transpose's reads
#pragma unroll
            for (int j = 0; j < 64; ++j) tbuf[lane * TROW + j] = re[j];
            __syncthreads();
#pragma unroll
            for (int j = 0; j < 64; ++j) re[j] = tbuf[j * TROW + lane];
            __syncthreads();
#pragma unroll
            for (int j = 0; j < 64; ++j) tbuf[lane * TROW + j] = im[j];
            __syncthreads();
#pragma unroll
            for (int j = 0; j < 64; ++j) im[j] = tbuf[j * TROW + lane];
        }
    }

    // --- measurement in P0: probs, 12 Z-expectations ---
    float tot = 0.f, s6 = 0.f, s7 = 0.f, s8 = 0.f, s9 = 0.f, s10 = 0.f, s11 = 0.f;
#pragma unroll
    for (int j = 0; j < 64; ++j) {
        const float p = re[j] * re[j] + im[j] * im[j];
        tot += p;
        s6  += (j & 32) ? -p : p;  // wire 6  <-> j bit 5
        s7  += (j & 16) ? -p : p;
        s8  += (j & 8)  ? -p : p;
        s9  += (j & 4)  ? -p : p;
        s10 += (j & 2)  ? -p : p;
        s11 += (j & 1)  ? -p : p;  // wire 11 <-> j bit 0
    }
    float part[NQ];
#pragma unroll
    for (int q = 0; q < 6; ++q)
        part[q] = ((lane >> (5 - q)) & 1) ? -tot : tot;
    part[6] = s6; part[7] = s7; part[8] = s8;
    part[9] = s9; part[10] = s10; part[11] = s11;

#pragma unroll
    for (int off = 32; off > 0; off >>= 1) {
#pragma unroll
        for (int q = 0; q < NQ; ++q)
            part[q] += __shfl_down(part[q], off, 64);
    }
    if (lane == 0) {
#pragma unroll
        for (int q = 0; q < NQ; ++q) redq[q] = part[q];
    }
    __syncthreads();

    if (lane < NA) {
        float acc = fc_b[lane];
#pragma unroll
        for (int q = 0; q < NQ; ++q)
            acc += redq[q] * fc_w[lane * NQ + q];
        out[b * NA + lane] = acc;
    }
}

extern "C" void kernel_launch(void* const* d_in, const int* in_sizes, int n_in,
                              void* d_out, int out_size, void* d_ws, size_t ws_size,
                              hipStream_t stream) {
    const float* x   = (const float*)d_in[0];
    const float* w   = (const float*)d_in[1];
    const float* fcw = (const float*)d_in[2];
    const float* fcb = (const float*)d_in[3];
    qdqn_kernel<<<BATCH, 64, 0, stream>>>(x, w, fcw, fcb, (float*)d_out);
}

// Round 3
// 204.959 us; speedup vs baseline: 2.2112x; 1.1189x over previous
//
#include <hip/hip_runtime.h>
#include <math.h>

#define NQ 12
#define DIM 4096
#define NL 4
#define NA 6
#define BATCH 4096
#define TROW 65  // odd f32 stride -> conflict-free transpose both directions

typedef float f2 __attribute__((ext_vector_type(2)));

// Complex packed-f32 primitives. State/coeff layout: (re, im) in a VGPR pair.
//   CMUL : d = (u.re*a.re, u.re*a.im)              -- real part of u times a
//   CMACR: d += (u.re*a.re, u.re*a.im)
//   CMACI: d += (-u.im*a.im, u.im*a.re)            -- i*u.im times a
// CMUL+CMACI = complex multiply u*a; +CMACR+CMACI = accumulate another u'*a'.
#define CMUL(d, u, a)  asm("v_pk_mul_f32 %0, %1, %2 op_sel_hi:[0,1]"                 : "=v"(d) : "v"(u), "v"(a))
#define CMACR(d, u, a) asm("v_pk_fma_f32 %0, %1, %2, %0 op_sel_hi:[0,1,1]"           : "+v"(d) : "v"(u), "v"(a))
#define CMACI(d, u, a) asm("v_pk_fma_f32 %0, %1, %2, %0 op_sel:[1,1,0] op_sel_hi:[1,0,1] neg_lo:[1,0,0]" : "+v"(d) : "v"(u), "v"(a))

// Single-wave workgroup: LDS ordering needs only lgkmcnt drain, not s_barrier.
#define WFENCE() asm volatile("s_waitcnt lgkmcnt(0)" ::: "memory")

// Layouts: P0: amp index i = (lane<<6)|j ; P1: i = (j<<6)|lane.
// Schedule (verified R2): g=0..7, l=g>>1, hi = gates on wires 6..11 (layout P0):
//   G0(L0 hi,P0) T G1(L0 lo,P1) CZ0 G2(L1 lo,P1) T G3(L1 hi,P0) CZ1
//   G4(L2 hi,P0) T G5(L2 lo,P1) CZ2 G6(L3 lo,P1) T G7(L3 hi,P0) CZ3, measure in P0.

__global__ __launch_bounds__(64) void qdqn_kernel(
    const float* __restrict__ x,       // [BATCH,12]
    const float* __restrict__ weights, // [4,12,3]
    const float* __restrict__ fc_w,    // [6,12]
    const float* __restrict__ fc_b,    // [6]
    float* __restrict__ out)           // [BATCH,6]
{
    __shared__ __align__(16) float tbuf[64 * TROW];   // 16640 B
    __shared__ __align__(16) f2 rotc[NL * NQ][4];     // u00,u01,u10,u11 as (re,im)
    __shared__ float encc[NQ], encs[NQ];
    __shared__ float redq[NQ];

    const int lane = threadIdx.x;
    const int b = blockIdx.x;

    // --- setup: 48 rot matrices (lanes 0..47), encoding sincos (lanes 48..59) ---
    if (lane < NL * NQ) {
        float phi = weights[lane * 3 + 0];
        float th  = weights[lane * 3 + 1];
        float om  = weights[lane * 3 + 2];
        float st, ct, sa, ca, sb, cb;
        sincosf(0.5f * th, &st, &ct);
        sincosf(0.5f * (phi + om), &sa, &ca);
        sincosf(0.5f * (phi - om), &sb, &cb);
        rotc[lane][0] = (f2){ ca * ct, -sa * ct };  // u00
        rotc[lane][1] = (f2){ -cb * st, -sb * st }; // u01
        rotc[lane][2] = (f2){ cb * st, -sb * st };  // u10
        rotc[lane][3] = (f2){ ca * ct,  sa * ct };  // u11
    } else if (lane < NL * NQ + NQ) {
        int q = lane - NL * NQ;
        float s, c;
        sincosf(0.5f * x[b * NQ + q], &s, &c);
        encc[q] = c; encs[q] = s;
    }
    __syncthreads();

    float ec[NQ], es[NQ];
#pragma unroll
    for (int q = 0; q < NQ; ++q) { ec[q] = encc[q]; es[q] = encs[q]; }

    // --- RY product state in P0, packed (re,im) ---
    f2 st[64];
    float pre = 1.0f;
#pragma unroll
    for (int q = 0; q < 6; ++q)
        pre *= ((lane >> (5 - q)) & 1) ? es[q] : ec[q];
#pragma unroll
    for (int j = 0; j < 64; ++j) {
        float v = pre;
#pragma unroll
        for (int q = 6; q < NQ; ++q)
            v *= ((j >> (11 - q)) & 1) ? es[q] : ec[q];
        st[j] = (f2){ v, 0.0f };
    }

    const float slane = (__popc(lane & (lane >> 1)) & 1) ? -1.0f : 1.0f;

#pragma unroll 1
    for (int g = 0; g < 8; ++g) {
        const int l = g >> 1;
        const bool hi = (((g + 1) & 2) == 0);

        // --- 6 register-local complex butterflies, 8 pk ops per pair ---
#pragma unroll
        for (int bit = 0; bit < 6; ++bit) {
            const int wire = hi ? (11 - bit) : (5 - bit);
            const f2 u00 = rotc[l * NQ + wire][0];
            const f2 u01 = rotc[l * NQ + wire][1];
            const f2 u10 = rotc[l * NQ + wire][2];
            const f2 u11 = rotc[l * NQ + wire][3];
            const int S = 1 << bit;
#pragma unroll
            for (int m = 0; m < 32; ++m) {
                const int j0 = ((m & ~(S - 1)) << 1) | (m & (S - 1));
                const int j1 = j0 + S;
                const f2 a0 = st[j0];
                const f2 a1 = st[j1];
                f2 n0, n1;
                CMUL (n0, u00, a0);
                CMACI(n0, u00, a0);
                CMACR(n0, u01, a1);
                CMACI(n0, u01, a1);
                CMUL (n1, u10, a0);
                CMACI(n1, u10, a0);
                CMACR(n1, u11, a1);
                CMACI(n1, u11, a1);
                st[j0] = n0;
                st[j1] = n1;
            }
        }

        if (g & 1) {
            // --- CZ diagonal (layout-aware, verified R2) ---
            const float flip = ((hi ? lane : (lane >> 5)) & 1) ? -slane : slane;
#pragma unroll
            for (int j = 0; j < 64; ++j) {
                const float fb0 = (hi ? (j >= 32) : ((j & 1) != 0)) ? flip : slane;
                const float f = (__popc(j & (j >> 1)) & 1) ? -fb0 : fb0;
                st[j] *= f;
            }
        } else {
            // --- 64x64 transpose via LDS, component-wise, fence-only sync ---
            WFENCE();
#pragma unroll
            for (int j = 0; j < 64; ++j) tbuf[lane * TROW + j] = st[j].x;
            WFENCE();
#pragma unroll
            for (int j = 0; j < 64; ++j) st[j].x = tbuf[j * TROW + lane];
            WFENCE();
#pragma unroll
            for (int j = 0; j < 64; ++j) tbuf[lane * TROW + j] = st[j].y;
            WFENCE();
#pragma unroll
            for (int j = 0; j < 64; ++j) st[j].y = tbuf[j * TROW + lane];
        }
    }

    // --- measurement in P0 ---
    float tot = 0.f, s6 = 0.f, s7 = 0.f, s8 = 0.f, s9 = 0.f, s10 = 0.f, s11 = 0.f;
#pragma unroll
    for (int j = 0; j < 64; ++j) {
        const float p = st[j].x * st[j].x + st[j].y * st[j].y;
        tot += p;
        s6  += (j & 32) ? -p : p;
        s7  += (j & 16) ? -p : p;
        s8  += (j & 8)  ? -p : p;
        s9  += (j & 4)  ? -p : p;
        s10 += (j & 2)  ? -p : p;
        s11 += (j & 1)  ? -p : p;
    }
    float part[NQ];
#pragma unroll
    for (int q = 0; q < 6; ++q)
        part[q] = ((lane >> (5 - q)) & 1) ? -tot : tot;
    part[6] = s6; part[7] = s7; part[8] = s8;
    part[9] = s9; part[10] = s10; part[11] = s11;

#pragma unroll
    for (int off = 32; off > 0; off >>= 1) {
#pragma unroll
        for (int q = 0; q < NQ; ++q)
            part[q] += __shfl_down(part[q], off, 64);
    }
    if (lane == 0) {
#pragma unroll
        for (int q = 0; q < NQ; ++q) redq[q] = part[q];
    }
    WFENCE();

    if (lane < NA) {
        float acc = fc_b[lane];
#pragma unroll
        for (int q = 0; q < NQ; ++q)
            acc += redq[q] * fc_w[lane * NQ + q];
        out[b * NA + lane] = acc;
    }
}

extern "C" void kernel_launch(void* const* d_in, const int* in_sizes, int n_in,
                              void* d_out, int out_size, void* d_ws, size_t ws_size,
                              hipStream_t stream) {
    const float* x   = (const float*)d_in[0];
    const float* w   = (const float*)d_in[1];
    const float* fcw = (const float*)d_in[2];
    const float* fcb = (const float*)d_in[3];
    qdqn_kernel<<<BATCH, 64, 0, stream>>>(x, w, fcw, fcb, (float*)d_out);
}

// Round 4
// 197.484 us; speedup vs baseline: 2.2949x; 1.0379x over previous
//
#include <hip/hip_runtime.h>
#include <math.h>

#define NQ 12
#define NL 4
#define NA 6
#define BATCH 4096
#define NT 128   // 2 waves; lane = t&63 (wires 0..5), w = t>>6 (wire 6), 5 reg bits (wires 7..11 in P0)

typedef float f2 __attribute__((ext_vector_type(2)));

// HW-verified (R3 end-to-end) packed complex primitives; state/coeff = (re,im) in a VGPR pair.
#define CMUL(d, u, a)  asm("v_pk_mul_f32 %0, %1, %2 op_sel_hi:[0,1]"                 : "=v"(d) : "v"(u), "v"(a))
#define CMACR(d, u, a) asm("v_pk_fma_f32 %0, %1, %2, %0 op_sel_hi:[0,1,1]"           : "+v"(d) : "v"(u), "v"(a))
#define CMACI(d, u, a) asm("v_pk_fma_f32 %0, %1, %2, %0 op_sel:[1,1,0] op_sel_hi:[1,0,1] neg_lo:[1,0,0]" : "+v"(d) : "v"(u), "v"(a))
#define WFENCE() asm volatile("s_waitcnt lgkmcnt(0)" ::: "memory")

#define BFLY(A0, A1, U00, U01, U10, U11) do { \
    f2 _a0 = (A0), _a1 = (A1), _n0, _n1; \
    CMUL (_n0, U00, _a0); CMACI(_n0, U00, _a0); \
    CMACR(_n0, U01, _a1); CMACI(_n0, U01, _a1); \
    CMUL (_n1, U10, _a0); CMACI(_n1, U10, _a0); \
    CMACR(_n1, U11, _a1); CMACI(_n1, U11, _a1); \
    (A0) = _n0; (A1) = _n1; } while (0)

// Layouts (amp index i, 12 bits):
//  P0: i = (lane<<6)|(w<<5)|j   wires 0..5 = lane bits 5..0, wire6 = w, wires 7..11 = j bits 4..0
//  P1: i = (j<<7)|(l0<<6)|(w<<5)|(lane>>1)  wires 0..4 = j bits, wire5 = l0, wire6 = w, wires 7..11 = lane bits 5..1
// Transpose P0<->P1 (involution, wave-local): new st[j'] of lane L = old st[L>>1] of lane (j'<<1)|(L&1).

__global__ __launch_bounds__(NT, 4) void qdqn_kernel(
    const float* __restrict__ x,       // [BATCH,12]
    const float* __restrict__ weights, // [4,12,3]
    const float* __restrict__ fc_w,    // [6,12]
    const float* __restrict__ fc_b,    // [6]
    float* __restrict__ out)           // [BATCH,6]
{
    __shared__ __align__(16) float tbx[2][64 * 33];  // per-wave transpose halves; aliased by exchange
    __shared__ __align__(16) f2 rotc[NL * NQ][4];    // u00,u01,u10,u11 as (re,im)
    __shared__ float encc[NQ], encs[NQ];
    __shared__ float red[2][NQ];
    __shared__ float qout[NQ];

    const int tix  = threadIdx.x;
    const int lane = tix & 63;
    const int w    = tix >> 6;
    const int b    = blockIdx.x;

    // --- setup: 48 rot matrices (threads 0..47), encoding sincos (threads 64..75) ---
    if (tix < NL * NQ) {
        float phi = weights[tix * 3 + 0];
        float th  = weights[tix * 3 + 1];
        float om  = weights[tix * 3 + 2];
        float sth, cth, sa, ca, sb, cb;
        sincosf(0.5f * th, &sth, &cth);
        sincosf(0.5f * (phi + om), &sa, &ca);
        sincosf(0.5f * (phi - om), &sb, &cb);
        rotc[tix][0] = (f2){ ca * cth, -sa * cth };  // u00
        rotc[tix][1] = (f2){ -cb * sth, -sb * sth }; // u01
        rotc[tix][2] = (f2){ cb * sth, -sb * sth };  // u10
        rotc[tix][3] = (f2){ ca * cth,  sa * cth };  // u11
    } else if (tix >= 64 && tix < 64 + NQ) {
        int q = tix - 64;
        float s, c;
        sincosf(0.5f * x[b * NQ + q], &s, &c);
        encc[q] = c; encs[q] = s;
    }
    __syncthreads();

    // --- RY product state in P0 ---
    f2 st[32];
    {
        float pre = w ? encs[6] : encc[6];
#pragma unroll
        for (int q = 0; q < 6; ++q)
            pre *= ((lane >> (5 - q)) & 1) ? encs[q] : encc[q];
        const float c7 = encc[7],  s7 = encs[7];
        const float c8 = encc[8],  s8 = encs[8];
        const float c9 = encc[9],  s9 = encs[9];
        const float cA = encc[10], sA = encs[10];
        const float cB = encc[11], sB = encs[11];
#pragma unroll
        for (int j = 0; j < 32; ++j) {
            float v = pre;
            v *= (j & 16) ? s7 : c7;
            v *= (j & 8)  ? s8 : c8;
            v *= (j & 4)  ? s9 : c9;
            v *= (j & 2)  ? sA : cA;
            v *= (j & 1)  ? sB : cB;
            st[j] = (f2){ v, 0.0f };
        }
    }

    float* const tb = &tbx[w][0];
    f2*    const xb = (f2*)&tbx[0][0];
    const int prt = tix ^ 64;

#pragma unroll 1
    for (int h = 0; h < 2; ++h) {
        // ================= even layer l = 2h (entry P0, exit P1) =================
        {
            const int gb = (2 * h) * NQ;
            // reg gates wires 7..11 (P0: wire 11-bq <-> j bit bq)
#pragma unroll
            for (int bq = 0; bq < 5; ++bq) {
                const f2 u00 = rotc[gb + 11 - bq][0], u01 = rotc[gb + 11 - bq][1];
                const f2 u10 = rotc[gb + 11 - bq][2], u11 = rotc[gb + 11 - bq][3];
                const int S = 1 << bq;
#pragma unroll
                for (int m = 0; m < 16; ++m) {
                    const int j0 = ((m & ~(S - 1)) << 1) | (m & (S - 1));
                    BFLY(st[j0], st[j0 + S], u00, u01, u10, u11);
                }
            }
            // wave-local transpose P0 -> P1 (x then y)
            WFENCE();
#pragma unroll
            for (int j = 0; j < 32; ++j) tb[lane * 33 + j] = st[j].x;
            WFENCE();
#pragma unroll
            for (int j = 0; j < 32; ++j) st[j].x = tb[((j << 1) | (lane & 1)) * 33 + (lane >> 1)];
            WFENCE();
#pragma unroll
            for (int j = 0; j < 32; ++j) tb[lane * 33 + j] = st[j].y;
            WFENCE();
#pragma unroll
            for (int j = 0; j < 32; ++j) st[j].y = tb[((j << 1) | (lane & 1)) * 33 + (lane >> 1)];
            // reg gates wires 0..4 (P1: wire 4-bq <-> j bit bq)
#pragma unroll
            for (int bq = 0; bq < 5; ++bq) {
                const f2 u00 = rotc[gb + 4 - bq][0], u01 = rotc[gb + 4 - bq][1];
                const f2 u10 = rotc[gb + 4 - bq][2], u11 = rotc[gb + 4 - bq][3];
                const int S = 1 << bq;
#pragma unroll
                for (int m = 0; m < 16; ++m) {
                    const int j0 = ((m & ~(S - 1)) << 1) | (m & (S - 1));
                    BFLY(st[j0], st[j0 + S], u00, u01, u10, u11);
                }
            }
            // shuffle gate wire 5 (lane bit 0)
            {
                const f2 u00 = rotc[gb + 5][0], u01 = rotc[gb + 5][1];
                const f2 u10 = rotc[gb + 5][2], u11 = rotc[gb + 5][3];
                const int bit = lane & 1;
                const f2 ca = bit ? u11 : u00;
                const f2 cb = bit ? u10 : u01;
#pragma unroll
                for (int j = 0; j < 32; ++j) {
                    f2 as = st[j], ap, n;
                    ap.x = __shfl_xor(as.x, 1, 64);
                    ap.y = __shfl_xor(as.y, 1, 64);
                    CMUL(n, ca, as); CMACI(n, ca, as); CMACR(n, cb, ap); CMACI(n, cb, ap);
                    st[j] = n;
                }
            }
            // exchange gate wire 6 (w bit), chunked through shared scratch
            {
                const f2 u00 = rotc[gb + 6][0], u01 = rotc[gb + 6][1];
                const f2 u10 = rotc[gb + 6][2], u11 = rotc[gb + 6][3];
                const f2 ca = w ? u11 : u00;
                const f2 cb = w ? u10 : u01;
#pragma unroll
                for (int c = 0; c < 4; ++c) {
                    __syncthreads();
#pragma unroll
                    for (int k = 0; k < 8; ++k) xb[tix * 9 + k] = st[c * 8 + k];
                    __syncthreads();
#pragma unroll
                    for (int k = 0; k < 8; ++k) {
                        f2 as = st[c * 8 + k];
                        f2 ap = xb[prt * 9 + k];
                        f2 n;
                        CMUL(n, ca, as); CMACI(n, ca, as); CMACR(n, cb, ap); CMACI(n, cb, ap);
                        st[c * 8 + k] = n;
                    }
                }
                __syncthreads();
            }
            // CZ in P1: base = wires(7..10 pairs in lane bits) + (l0&w) + (w&l5); per-j: j-pairs + (j0&l0)
            {
                const int par = __popc(lane & (lane >> 1) & 0x1E)
                              + ((lane & 1) & w) + (w & (lane >> 5) & 1);
                const float base = (par & 1) ? -1.0f : 1.0f;
                const float sOdd = (lane & 1) ? -base : base;  // extra (j&1)&(lane&1) term
#pragma unroll
                for (int j = 0; j < 32; ++j) {
                    float s = (j & 1) ? sOdd : base;
                    if (__popc(j & (j >> 1)) & 1) s = -s;      // compile-time per j
                    st[j] *= s;
                }
            }
        }
        // ================= odd layer l = 2h+1 (entry P1, exit P0) =================
        {
            const int gb = (2 * h + 1) * NQ;
            // reg gates wires 0..4 (P1)
#pragma unroll
            for (int bq = 0; bq < 5; ++bq) {
                const f2 u00 = rotc[gb + 4 - bq][0], u01 = rotc[gb + 4 - bq][1];
                const f2 u10 = rotc[gb + 4 - bq][2], u11 = rotc[gb + 4 - bq][3];
                const int S = 1 << bq;
#pragma unroll
                for (int m = 0; m < 16; ++m) {
                    const int j0 = ((m & ~(S - 1)) << 1) | (m & (S - 1));
                    BFLY(st[j0], st[j0 + S], u00, u01, u10, u11);
                }
            }
            // wave-local transpose P1 -> P0
            WFENCE();
#pragma unroll
            for (int j = 0; j < 32; ++j) tb[lane * 33 + j] = st[j].x;
            WFENCE();
#pragma unroll
            for (int j = 0; j < 32; ++j) st[j].x = tb[((j << 1) | (lane & 1)) * 33 + (lane >> 1)];
            WFENCE();
#pragma unroll
            for (int j = 0; j < 32; ++j) tb[lane * 33 + j] = st[j].y;
            WFENCE();
#pragma unroll
            for (int j = 0; j < 32; ++j) st[j].y = tb[((j << 1) | (lane & 1)) * 33 + (lane >> 1)];
            // reg gates wires 7..11 (P0)
#pragma unroll
            for (int bq = 0; bq < 5; ++bq) {
                const f2 u00 = rotc[gb + 11 - bq][0], u01 = rotc[gb + 11 - bq][1];
                const f2 u10 = rotc[gb + 11 - bq][2], u11 = rotc[gb + 11 - bq][3];
                const int S = 1 << bq;
#pragma unroll
                for (int m = 0; m < 16; ++m) {
                    const int j0 = ((m & ~(S - 1)) << 1) | (m & (S - 1));
                    BFLY(st[j0], st[j0 + S], u00, u01, u10, u11);
                }
            }
            // shuffle gate wire 5
            {
                const f2 u00 = rotc[gb + 5][0], u01 = rotc[gb + 5][1];
                const f2 u10 = rotc[gb + 5][2], u11 = rotc[gb + 5][3];
                const int bit = lane & 1;
                const f2 ca = bit ? u11 : u00;
                const f2 cb = bit ? u10 : u01;
#pragma unroll
                for (int j = 0; j < 32; ++j) {
                    f2 as = st[j], ap, n;
                    ap.x = __shfl_xor(as.x, 1, 64);
                    ap.y = __shfl_xor(as.y, 1, 64);
                    CMUL(n, ca, as); CMACI(n, ca, as); CMACR(n, cb, ap); CMACI(n, cb, ap);
                    st[j] = n;
                }
            }
            // exchange gate wire 6
            {
                const f2 u00 = rotc[gb + 6][0], u01 = rotc[gb + 6][1];
                const f2 u10 = rotc[gb + 6][2], u11 = rotc[gb + 6][3];
                const f2 ca = w ? u11 : u00;
                const f2 cb = w ? u10 : u01;
#pragma unroll
                for (int c = 0; c < 4; ++c) {
                    __syncthreads();
#pragma unroll
                    for (int k = 0; k < 8; ++k) xb[tix * 9 + k] = st[c * 8 + k];
                    __syncthreads();
#pragma unroll
                    for (int k = 0; k < 8; ++k) {
                        f2 as = st[c * 8 + k];
                        f2 ap = xb[prt * 9 + k];
                        f2 n;
                        CMUL(n, ca, as); CMACI(n, ca, as); CMACR(n, cb, ap); CMACI(n, cb, ap);
                        st[c * 8 + k] = n;
                    }
                }
                __syncthreads();
            }
            // CZ in P0: base = all 5 lane pairs + (l0&w); per-j: (w & j4) + j-pairs
            {
                const int par = __popc(lane & (lane >> 1)) + ((lane & 1) & w);
                const float base = (par & 1) ? -1.0f : 1.0f;
                const float sHi = w ? -base : base;  // extra (w & (j>>4)) term for j >= 16
#pragma unroll
                for (int j = 0; j < 32; ++j) {
                    float s = (j & 16) ? sHi : base;
                    if (__popc(j & (j >> 1)) & 1) s = -s;  // compile-time per j
                    st[j] *= s;
                }
            }
        }
    }

    // --- measurement in P0 ---
    float tot = 0.f, m7 = 0.f, m8 = 0.f, m9 = 0.f, m10 = 0.f, m11 = 0.f;
#pragma unroll
    for (int j = 0; j < 32; ++j) {
        const float p = st[j].x * st[j].x + st[j].y * st[j].y;
        tot += p;
        m7  += (j & 16) ? -p : p;
        m8  += (j & 8)  ? -p : p;
        m9  += (j & 4)  ? -p : p;
        m10 += (j & 2)  ? -p : p;
        m11 += (j & 1)  ? -p : p;
    }
    float part[NQ];
#pragma unroll
    for (int q = 0; q < 6; ++q)
        part[q] = ((lane >> (5 - q)) & 1) ? -tot : tot;
    part[6] = w ? -tot : tot;
    part[7] = m7; part[8] = m8; part[9] = m9; part[10] = m10; part[11] = m11;

#pragma unroll
    for (int off = 32; off > 0; off >>= 1) {
#pragma unroll
        for (int q = 0; q < NQ; ++q)
            part[q] += __shfl_down(part[q], off, 64);
    }
    if (lane == 0) {
#pragma unroll
        for (int q = 0; q < NQ; ++q) red[w][q] = part[q];
    }
    __syncthreads();
    if (tix < NQ) qout[tix] = red[0][tix] + red[1][tix];
    __syncthreads();

    if (tix < NA) {
        float acc = fc_b[tix];
#pragma unroll
        for (int q = 0; q < NQ; ++q)
            acc += qout[q] * fc_w[tix * NQ + q];
        out[b * NA + tix] = acc;
    }
}

extern "C" void kernel_launch(void* const* d_in, const int* in_sizes, int n_in,
                              void* d_out, int out_size, void* d_ws, size_t ws_size,
                              hipStream_t stream) {
    const float* x   = (const float*)d_in[0];
    const float* w   = (const float*)d_in[1];
    const float* fcw = (const float*)d_in[2];
    const float* fcb = (const float*)d_in[3];
    qdqn_kernel<<<BATCH, NT, 0, stream>>>(x, w, fcw, fcb, (float*)d_out);
}